// Round 5
// baseline (55.878 us; speedup 1.0000x reference)
//
#include <hip/hip_runtime.h>
#include <math.h>

#define CUTOFF 5.0f
#define BLOCK 256
#define EPT 4
#define TILE (BLOCK * EPT)          // 1024 edges per tile
#define CHUNK 4                     // consecutive tiles per block

#define N_SYS 8
#define N_AT  1024
#define EPS   (N_AT * (N_AT - 1))   // 1047552 edges per system
#define CLPAD (N_AT + N_AT / 8)     // padded SoA: idx(b)=b+(b>>3) -> stride-4 reads = 2-way

typedef float floatx4 __attribute__((ext_vector_type(4)));

__device__ __forceinline__ unsigned pidx(unsigned b) { return b + (b >> 3); }

// Lane owns 4 CONSECUTIVE edges -> 20 contiguous output floats -> 5 direct
// float4 stores (L2 write-combines the 80B-stride pattern into full lines).
// Coords live in padded-SoA LDS so the stride-4 atom gather is conflict-free.
// No output staging, no per-tile barriers; barrier only on system change.
__global__ __launch_bounds__(BLOCK, 8) void graph_edges_structured(
    const float* __restrict__ coords,
    float*       __restrict__ out,
    int E)
{
    __shared__ float clx[CLPAD];
    __shared__ float cly[CLPAD];
    __shared__ float clz[CLPAD];
    const float PI_OVER_C = 3.14159265358979323846f / CUTOFF;
    const int t = threadIdx.x;
    const int ntiles = E / TILE;          // 8184
    const int tile0 = blockIdx.x * CHUNK;
    unsigned cur_sys = 0xFFFFFFFFu;

    for (int tile = tile0; tile < tile0 + CHUNK && tile < ntiles; ++tile) {
        const int base = tile * TILE;
        const unsigned sys   = (unsigned)base / (unsigned)EPS;   // magic-mul
        const unsigned rbase = (unsigned)base - sys * (unsigned)EPS;

        if (sys != cur_sys) {
            __syncthreads();              // all waves done reading old coords
            // stage this system's coords into padded SoA.
            // thread t loads atoms 4t..4t+3 (3 float4 = 12 floats), scatters
            // with compile-time component mapping; write stride 4 -> 2-way.
            const floatx4* g = (const floatx4*)(coords + (size_t)sys * (3u * N_AT));
            floatx4 v0 = g[3 * t + 0];
            floatx4 v1 = g[3 * t + 1];
            floatx4 v2 = g[3 * t + 2];
            float f[12] = { v0[0], v0[1], v0[2], v0[3],
                            v1[0], v1[1], v1[2], v1[3],
                            v2[0], v2[1], v2[2], v2[3] };
            unsigned a0 = 4u * (unsigned)t;
#pragma unroll
            for (int i = 0; i < 4; ++i) {
                unsigned p = pidx(a0 + i);
                clx[p] = f[3 * i + 0];
                cly[p] = f[3 * i + 1];
                clz[p] = f[3 * i + 2];
            }
            __syncthreads();              // coords ready
            cur_sys = sys;
        }

        const unsigned r0 = rbase + 4u * (unsigned)t;
        float vals[20];
#pragma unroll
        for (int k = 0; k < EPT; ++k) {
            unsigned r = r0 + (unsigned)k;
            unsigned a = r / 1023u;                  // magic-mul
            unsigned m = r - a * 1023u;
            unsigned b = m + (m >= a ? 1u : 0u);
            unsigned ia = pidx(a);                   // ~wave-uniform: broadcast
            unsigned ib = pidx(b);                   // stride-4 padded -> 2-way, free

            float x = clx[ib] - clx[ia];
            float y = cly[ib] - cly[ia];
            float z = clz[ib] - clz[ia];
            float d = sqrtf(x * x + y * y + z * z);
            float c = 0.5f * __cosf(d * PI_OVER_C) + 0.5f;

            vals[5 * k + 0] = x;
            vals[5 * k + 1] = y;
            vals[5 * k + 2] = z;
            vals[5 * k + 3] = d;
            vals[5 * k + 4] = (d < CUTOFF) ? c : 0.0f;
        }

        // 20 contiguous floats -> 5 float4 stores through L2 (write-combined)
        floatx4* ov = (floatx4*)(out + (size_t)base * 5u + 20u * (unsigned)t);
#pragma unroll
        for (int q = 0; q < 5; ++q) {
            floatx4 o = { vals[4 * q + 0], vals[4 * q + 1],
                          vals[4 * q + 2], vals[4 * q + 3] };
            ov[q] = o;
        }
    }
}

// General fallback: reads index arrays (round-1 verified kernel).
__global__ __launch_bounds__(BLOCK) void graph_edges_general(
    const float* __restrict__ coords,
    const int*   __restrict__ esrc,
    const int*   __restrict__ edst,
    float*       __restrict__ out,
    int E)
{
    __shared__ float buf[BLOCK * 5];
    const float PI_OVER_C = 3.14159265358979323846f / CUTOFF;
    const int t = threadIdx.x;

    for (int base = blockIdx.x * BLOCK; base < E; base += gridDim.x * BLOCK) {
        int e = base + t;
        float vx = 0.f, vy = 0.f, vz = 0.f, d = 0.f, sw = 0.f;
        if (e < E) {
            int s  = esrc[e];
            int dd = edst[e];
            float sx = coords[3 * s + 0];
            float sy = coords[3 * s + 1];
            float sz = coords[3 * s + 2];
            float tx = coords[3 * dd + 0];
            float ty = coords[3 * dd + 1];
            float tz = coords[3 * dd + 2];
            vx = tx - sx; vy = ty - sy; vz = tz - sz;
            d = sqrtf(vx * vx + vy * vy + vz * vz);
            sw = (d < CUTOFF) ? (0.5f * __cosf(d * PI_OVER_C) + 0.5f) : 0.0f;
        }
        buf[t * 5 + 0] = vx;
        buf[t * 5 + 1] = vy;
        buf[t * 5 + 2] = vz;
        buf[t * 5 + 3] = d;
        buf[t * 5 + 4] = sw;
        __syncthreads();
        int remaining = E - base;
        int n = (remaining < BLOCK ? remaining : BLOCK) * 5;
        int ob = base * 5;
        for (int k = t; k < n; k += BLOCK) {
            out[ob + k] = buf[k];
        }
        __syncthreads();
    }
}

extern "C" void kernel_launch(void* const* d_in, const int* in_sizes, int n_in,
                              void* d_out, int out_size, void* d_ws, size_t ws_size,
                              hipStream_t stream) {
    const float* coords = (const float*)d_in[0];
    const int*   esrc   = (const int*)d_in[1];
    const int*   edst   = (const int*)d_in[2];
    float*       out    = (float*)d_out;

    int E = in_sizes[1];

    if (E == N_SYS * EPS) {
        int ntiles = E / TILE;                        // 8184
        int grid   = (ntiles + CHUNK - 1) / CHUNK;    // 2046 blocks, 4 consecutive tiles each
        graph_edges_structured<<<grid, BLOCK, 0, stream>>>(coords, out, E);
    } else {
        int blocks_needed = (E + BLOCK - 1) / BLOCK;
        int grid = blocks_needed < 2048 ? blocks_needed : 2048;
        graph_edges_general<<<grid, BLOCK, 0, stream>>>(coords, esrc, edst, out, E);
    }
}

// Round 6
// 37.329 us; speedup vs baseline: 1.4969x; 1.4969x over previous
//
#include <hip/hip_runtime.h>
#include <math.h>

#define CUTOFF 5.0f
#define BLOCK 256
#define WAVES 4                     // BLOCK/64
#define EPT 4
#define TILE (BLOCK * EPT)          // 1024 edges per tile
#define CHUNK 4                     // consecutive tiles per block

#define N_SYS 8
#define N_AT  1024
#define EPS   (N_AT * (N_AT - 1))   // 1047552 edges per system
#define CLPAD (N_AT + N_AT / 8)     // padded SoA: idx(b)=b+(b>>3) -> stride-4 reads ~2-way

typedef float floatx4 __attribute__((ext_vector_type(4)));

__device__ __forceinline__ unsigned pidx(unsigned b) { return b + (b >> 3); }

// Wave-private LDS transpose, zero barriers in the tile loop:
//  - lane l of wave w owns 4 CONSECUTIVE edges (tile + w*256 + 4l + k)
//  - writes its 20 floats as 5 ds_write_b128 into the wave's obuf slice,
//    which holds the exact output image of those 256 edges
//  - reads back 5 contiguous ds_read_b128 and issues 5 dense nontemporal
//    global_store_dwordx4 (wave covers 1024B per store instr)
// Same wave produces and consumes -> in-order LDS, no __syncthreads needed.
// Bank math (8-lane groups): write word-off 20l mod 32 = {0,20,8,28,16,4,24,12}
// tiles all 32 banks; read word-off 4l tiles all 32 banks. Conflict-free.
__global__ __launch_bounds__(BLOCK, 4) void graph_edges_structured(
    const float* __restrict__ coords,
    float*       __restrict__ out,
    int E)
{
    __shared__ float clx[CLPAD];
    __shared__ float cly[CLPAD];
    __shared__ float clz[CLPAD];
    __shared__ floatx4 obuf[WAVES * 320];   // 20 KB: per-wave 256-edge output image

    const float PI_OVER_C = 3.14159265358979323846f / CUTOFF;
    const int t = threadIdx.x;
    const int w = t >> 6;                   // wave id
    const int l = t & 63;                   // lane id
    const int ntiles = E / TILE;            // 8184
    const int tile0 = blockIdx.x * CHUNK;
    unsigned cur_sys = 0xFFFFFFFFu;

    for (int tile = tile0; tile < tile0 + CHUNK && tile < ntiles; ++tile) {
        const int base = tile * TILE;
        const unsigned sys   = (unsigned)base / (unsigned)EPS;   // magic-mul
        const unsigned rbase = (unsigned)base - sys * (unsigned)EPS;

        if (sys != cur_sys) {
            __syncthreads();                // all waves done reading old coords
            const floatx4* g = (const floatx4*)(coords + (size_t)sys * (3u * N_AT));
            floatx4 v0 = g[3 * t + 0];
            floatx4 v1 = g[3 * t + 1];
            floatx4 v2 = g[3 * t + 2];
            float f[12] = { v0[0], v0[1], v0[2], v0[3],
                            v1[0], v1[1], v1[2], v1[3],
                            v2[0], v2[1], v2[2], v2[3] };
            unsigned a0 = 4u * (unsigned)t;
#pragma unroll
            for (int i = 0; i < 4; ++i) {
                unsigned p = pidx(a0 + i);
                clx[p] = f[3 * i + 0];
                cly[p] = f[3 * i + 1];
                clz[p] = f[3 * i + 2];
            }
            __syncthreads();                // coords ready
            cur_sys = sys;
        }

        // ---- compute 4 consecutive edges; incremental div by 1023 ----
        const unsigned r0 = rbase + ((unsigned)w << 8) + 4u * (unsigned)l;
        unsigned a = r0 / 1023u;            // magic-mul once
        unsigned m = r0 - a * 1023u;

        float vals[20];
#pragma unroll
        for (int k = 0; k < EPT; ++k) {
            unsigned b = m + (m >= a ? 1u : 0u);
            unsigned ia = pidx(a);          // ~wave-uniform: broadcast
            unsigned ib = pidx(b);          // stride-4 padded -> ~2-way, free

            float x = clx[ib] - clx[ia];
            float y = cly[ib] - cly[ia];
            float z = clz[ib] - clz[ia];
            float d = sqrtf(x * x + y * y + z * z);
            float c = 0.5f * __cosf(d * PI_OVER_C) + 0.5f;

            vals[5 * k + 0] = x;
            vals[5 * k + 1] = y;
            vals[5 * k + 2] = z;
            vals[5 * k + 3] = d;
            vals[5 * k + 4] = (d < CUTOFF) ? c : 0.0f;

            // next consecutive r
            ++m;
            if (m >= 1023u) { m = 0u; ++a; }
        }

        // ---- wave-private transpose: 5 b128 writes ----
        const int wbase = w * 320;
#pragma unroll
        for (int q = 0; q < 5; ++q) {
            floatx4 o = { vals[4 * q + 0], vals[4 * q + 1],
                          vals[4 * q + 2], vals[4 * q + 3] };
            obuf[wbase + 5 * l + q] = o;
        }

        // ---- readback + dense stores: 5 b128 reads, 5 dwordx4 nt stores ----
        floatx4* outv = (floatx4*)(out + (size_t)base * 5u);
#pragma unroll
        for (int r5 = 0; r5 < 5; ++r5) {
            floatx4 o = obuf[wbase + r5 * 64 + l];
            __builtin_nontemporal_store(o, &outv[wbase + r5 * 64 + l]);
        }
        // no barrier: next tile's obuf writes are same-wave, in-order
    }
}

// General fallback: reads index arrays (round-1 verified kernel).
__global__ __launch_bounds__(BLOCK) void graph_edges_general(
    const float* __restrict__ coords,
    const int*   __restrict__ esrc,
    const int*   __restrict__ edst,
    float*       __restrict__ out,
    int E)
{
    __shared__ float buf[BLOCK * 5];
    const float PI_OVER_C = 3.14159265358979323846f / CUTOFF;
    const int t = threadIdx.x;

    for (int base = blockIdx.x * BLOCK; base < E; base += gridDim.x * BLOCK) {
        int e = base + t;
        float vx = 0.f, vy = 0.f, vz = 0.f, d = 0.f, sw = 0.f;
        if (e < E) {
            int s  = esrc[e];
            int dd = edst[e];
            float sx = coords[3 * s + 0];
            float sy = coords[3 * s + 1];
            float sz = coords[3 * s + 2];
            float tx = coords[3 * dd + 0];
            float ty = coords[3 * dd + 1];
            float tz = coords[3 * dd + 2];
            vx = tx - sx; vy = ty - sy; vz = tz - sz;
            d = sqrtf(vx * vx + vy * vy + vz * vz);
            sw = (d < CUTOFF) ? (0.5f * __cosf(d * PI_OVER_C) + 0.5f) : 0.0f;
        }
        buf[t * 5 + 0] = vx;
        buf[t * 5 + 1] = vy;
        buf[t * 5 + 2] = vz;
        buf[t * 5 + 3] = d;
        buf[t * 5 + 4] = sw;
        __syncthreads();
        int remaining = E - base;
        int n = (remaining < BLOCK ? remaining : BLOCK) * 5;
        int ob = base * 5;
        for (int k = t; k < n; k += BLOCK) {
            out[ob + k] = buf[k];
        }
        __syncthreads();
    }
}

extern "C" void kernel_launch(void* const* d_in, const int* in_sizes, int n_in,
                              void* d_out, int out_size, void* d_ws, size_t ws_size,
                              hipStream_t stream) {
    const float* coords = (const float*)d_in[0];
    const int*   esrc   = (const int*)d_in[1];
    const int*   edst   = (const int*)d_in[2];
    float*       out    = (float*)d_out;

    int E = in_sizes[1];

    if (E == N_SYS * EPS) {
        int ntiles = E / TILE;                        // 8184
        int grid   = (ntiles + CHUNK - 1) / CHUNK;    // 2046 blocks, 4 consecutive tiles each
        graph_edges_structured<<<grid, BLOCK, 0, stream>>>(coords, out, E);
    } else {
        int blocks_needed = (E + BLOCK - 1) / BLOCK;
        int grid = blocks_needed < 2048 ? blocks_needed : 2048;
        graph_edges_general<<<grid, BLOCK, 0, stream>>>(coords, esrc, edst, out, E);
    }
}

// Round 7
// 31.930 us; speedup vs baseline: 1.7500x; 1.1691x over previous
//
#include <hip/hip_runtime.h>
#include <math.h>

#define CUTOFF 5.0f

#define N_SYS 8
#define N_AT  1024
#define EPS   (N_AT * (N_AT - 1))   // 1047552 edges per system

// ---- producer-consumer structured kernel geometry ----
#define PC_BLOCK 512                // 8 waves: 6 producers + 2 consumers
#define NPROD 6
#define NCONS 2
#define PTILE (NPROD * 256)         // 1536 edges per step
#define STEPS 11                    // steps per block
#define BPS   62                    // blocks per system: 62*11*1536 == EPS
#define GRID  (N_SYS * BPS)         // 496 blocks
#define CLPAD 1152                  // N_AT + N_AT/8, padded float4 SoA
#define OB4   (PTILE * 5 / 4)       // 1920 float4 per buffer

typedef float floatx4 __attribute__((ext_vector_type(4)));

__device__ __forceinline__ unsigned pidx(unsigned b) { return b + (b >> 3); }

// 6 producer waves compute 256 consecutive edges each into a double-buffered
// LDS output image (b128 writes, bank-tiling pattern verified in R6).
// 2 consumer waves do nothing but ds_read_b128 -> dense global float4 stores
// (the "embedded fill kernel" that keeps HBM write queues full).
// Coords: padded float4 SoA; stride-4 gather hits all 8 bank-groups -> ~2-way.
__global__ __launch_bounds__(PC_BLOCK, 4) void graph_edges_pc(
    const float* __restrict__ coords,
    float*       __restrict__ out)
{
    __shared__ floatx4 cl4[CLPAD];      // 18.4 KB: one system, (x,y,z,0) padded
    __shared__ floatx4 obuf[2][OB4];    // 60 KB: double-buffered 1536-edge image

    const float PI_OVER_C = 3.14159265358979323846f / CUTOFF;
    const int t  = threadIdx.x;
    const int w  = t >> 6;              // wave id 0..7
    const int l  = t & 63;              // lane id
    const int bb = blockIdx.x;
    const unsigned sys  = (unsigned)bb / BPS;        // magic-mul
    const unsigned bidx = (unsigned)bb - sys * BPS;  // 0..61 within system

    // ---- stage this system's coords once (threads 0..255) ----
    if (t < 256) {
        const floatx4* g = (const floatx4*)(coords + (size_t)sys * (3u * N_AT));
        floatx4 v0 = g[3 * t + 0];
        floatx4 v1 = g[3 * t + 1];
        floatx4 v2 = g[3 * t + 2];
        float f[12] = { v0[0], v0[1], v0[2], v0[3],
                        v1[0], v1[1], v1[2], v1[3],
                        v2[0], v2[1], v2[2], v2[3] };
        unsigned a0 = 4u * (unsigned)t;
#pragma unroll
        for (int i = 0; i < 4; ++i) {
            floatx4 c = { f[3 * i + 0], f[3 * i + 1], f[3 * i + 2], 0.0f };
            cl4[pidx(a0 + i)] = c;
        }
    }
    __syncthreads();

    const unsigned rblock = (bidx * STEPS) * (unsigned)PTILE;  // edge offset in system

    // ---- produce step 0 into buf 0 ----
    if (w < NPROD) {
        const unsigned r0 = rblock + ((unsigned)w << 8) + 4u * (unsigned)l;
        unsigned a = r0 / 1023u;                 // magic-mul
        unsigned m = r0 - a * 1023u;
        float vals[20];
#pragma unroll
        for (int k = 0; k < 4; ++k) {
            unsigned b = m + (m >= a ? 1u : 0u);
            floatx4 ca = cl4[pidx(a)];           // ~broadcast
            floatx4 cb = cl4[pidx(b)];           // stride-4 padded -> ~2-way
            float x = cb[0] - ca[0], y = cb[1] - ca[1], z = cb[2] - ca[2];
            float d = sqrtf(x * x + y * y + z * z);
            float c = 0.5f * __cosf(d * PI_OVER_C) + 0.5f;
            vals[5 * k + 0] = x; vals[5 * k + 1] = y; vals[5 * k + 2] = z;
            vals[5 * k + 3] = d; vals[5 * k + 4] = (d < CUTOFF) ? c : 0.0f;
            ++m; if (m >= 1023u) { m = 0u; ++a; }
        }
        const int wb = w * 320 + 5 * l;
#pragma unroll
        for (int q = 0; q < 5; ++q) {
            floatx4 o = { vals[4 * q + 0], vals[4 * q + 1],
                          vals[4 * q + 2], vals[4 * q + 3] };
            obuf[0][wb + q] = o;
        }
    }
    __syncthreads();

    int buf = 0;
    for (int s = 0; s < STEPS; ++s) {
        if (w < NPROD) {
            // produce step s+1 into buf^1 while consumers drain buf
            if (s + 1 < STEPS) {
                const unsigned r0 = rblock + (unsigned)(s + 1) * PTILE
                                  + ((unsigned)w << 8) + 4u * (unsigned)l;
                unsigned a = r0 / 1023u;
                unsigned m = r0 - a * 1023u;
                float vals[20];
#pragma unroll
                for (int k = 0; k < 4; ++k) {
                    unsigned b = m + (m >= a ? 1u : 0u);
                    floatx4 ca = cl4[pidx(a)];
                    floatx4 cb = cl4[pidx(b)];
                    float x = cb[0] - ca[0], y = cb[1] - ca[1], z = cb[2] - ca[2];
                    float d = sqrtf(x * x + y * y + z * z);
                    float c = 0.5f * __cosf(d * PI_OVER_C) + 0.5f;
                    vals[5 * k + 0] = x; vals[5 * k + 1] = y; vals[5 * k + 2] = z;
                    vals[5 * k + 3] = d; vals[5 * k + 4] = (d < CUTOFF) ? c : 0.0f;
                    ++m; if (m >= 1023u) { m = 0u; ++a; }
                }
                const int wb = w * 320 + 5 * l;
#pragma unroll
                for (int q = 0; q < 5; ++q) {
                    floatx4 o = { vals[4 * q + 0], vals[4 * q + 1],
                                  vals[4 * q + 2], vals[4 * q + 3] };
                    obuf[buf ^ 1][wb + q] = o;
                }
            }
        } else {
            // consumers: pure streaming drain of buf -> dense stores
            const int cw = w - NPROD;            // 0..1
            floatx4* out4 = (floatx4*)out
                          + (size_t)sys * (size_t)(EPS * 5 / 4)
                          + (size_t)(rblock + (unsigned)s * PTILE) * 5u / 4u;
            const int o0 = cw * 64 + l;
#pragma unroll
            for (int r = 0; r < 15; ++r) {
                floatx4 v = obuf[buf][r * 128 + o0];
                out4[r * 128 + o0] = v;
            }
        }
        __syncthreads();
        buf ^= 1;
    }
}

// General fallback: reads index arrays (round-1 verified kernel).
__global__ __launch_bounds__(256) void graph_edges_general(
    const float* __restrict__ coords,
    const int*   __restrict__ esrc,
    const int*   __restrict__ edst,
    float*       __restrict__ out,
    int E)
{
    __shared__ float buf[256 * 5];
    const float PI_OVER_C = 3.14159265358979323846f / CUTOFF;
    const int t = threadIdx.x;

    for (int base = blockIdx.x * 256; base < E; base += gridDim.x * 256) {
        int e = base + t;
        float vx = 0.f, vy = 0.f, vz = 0.f, d = 0.f, sw = 0.f;
        if (e < E) {
            int s  = esrc[e];
            int dd = edst[e];
            float sx = coords[3 * s + 0];
            float sy = coords[3 * s + 1];
            float sz = coords[3 * s + 2];
            float tx = coords[3 * dd + 0];
            float ty = coords[3 * dd + 1];
            float tz = coords[3 * dd + 2];
            vx = tx - sx; vy = ty - sy; vz = tz - sz;
            d = sqrtf(vx * vx + vy * vy + vz * vz);
            sw = (d < CUTOFF) ? (0.5f * __cosf(d * PI_OVER_C) + 0.5f) : 0.0f;
        }
        buf[t * 5 + 0] = vx;
        buf[t * 5 + 1] = vy;
        buf[t * 5 + 2] = vz;
        buf[t * 5 + 3] = d;
        buf[t * 5 + 4] = sw;
        __syncthreads();
        int remaining = E - base;
        int n = (remaining < 256 ? remaining : 256) * 5;
        int ob = base * 5;
        for (int k = t; k < n; k += 256) {
            out[ob + k] = buf[k];
        }
        __syncthreads();
    }
}

extern "C" void kernel_launch(void* const* d_in, const int* in_sizes, int n_in,
                              void* d_out, int out_size, void* d_ws, size_t ws_size,
                              hipStream_t stream) {
    const float* coords = (const float*)d_in[0];
    const int*   esrc   = (const int*)d_in[1];
    const int*   edst   = (const int*)d_in[2];
    float*       out    = (float*)d_out;

    int E = in_sizes[1];

    if (E == N_SYS * EPS) {
        graph_edges_pc<<<GRID, PC_BLOCK, 0, stream>>>(coords, out);
    } else {
        int blocks_needed = (E + 255) / 256;
        int grid = blocks_needed < 2048 ? blocks_needed : 2048;
        graph_edges_general<<<grid, 256, 0, stream>>>(coords, esrc, edst, out, E);
    }
}